// Round 2
// baseline (175.556 us; speedup 1.0000x reference)
//
#include <hip/hip_runtime.h>

// Multi-scale deformable attention forward (fp32).
// value:              (N, Lin, nH, D)        float32
// spatial_shapes:     (L, 2)                 int32 or int64 (runtime-detected)
// level_start_index:  (L,)                   int32 or int64 (runtime-detected)
// sampling_locations: (N, Lq, nH, L, P, 2)   float32
// attention_weights:  (N, Lq, nH, L, P)      float32
// out:                (N, Lq, nH*D)          float32
#define NH 8
#define DD 32
#define LL 4
#define PP 4
#define PSTRIDE (NH * DD)   // floats per spatial position = 256

// Thread mapping: tid -> (n, q, h, c) with c in [0,8): float4 channel group.
// 8 consecutive threads cover one (n,q,h) sample unit -> each corner gather is
// a contiguous 128B read across the group (coalesced).
//
// R2: maximize memory-level parallelism. Load all loc/aw as float4 up front
// (12 loads, no deps), then per level compute all 16 corner offsets/weights
// before issuing all 16 gather loads back-to-back.
__global__ __launch_bounds__(256) void msda_fwd(
    const float* __restrict__ value,
    const int*   __restrict__ spatial_shapes,
    const int*   __restrict__ level_start,
    const float* __restrict__ sloc,
    const float* __restrict__ aw,
    float*       __restrict__ out,
    int N, int Lq, int Lin, int total)
{
    int tid = blockIdx.x * blockDim.x + threadIdx.x;
    if (tid >= total) return;

    const int c  = tid & 7;          // float4 group within D
    const int h  = (tid >> 3) & 7;   // head
    const int nq = tid >> 6;         // n*Lq + q
    const int n  = nq / Lq;

    // --- metadata (wave-uniform): detect int32 vs int64 layout ---
    const bool is64 = (spatial_shapes[1] == 0);
    int Hs[LL], Ws[LL], Ss[LL];
#pragma unroll
    for (int l = 0; l < LL; ++l) {
        if (is64) {
            Hs[l] = spatial_shapes[4 * l];
            Ws[l] = spatial_shapes[4 * l + 2];
            Ss[l] = level_start[2 * l];
        } else {
            Hs[l] = spatial_shapes[2 * l];
            Ws[l] = spatial_shapes[2 * l + 1];
            Ss[l] = level_start[l];
        }
    }

    const size_t nqh = (size_t)nq * NH + h;

    // ---- bulk-load sampling locations (32 floats) and weights (16 floats) ----
    const float4* __restrict__ loc4 = (const float4*)(sloc + nqh * (LL * PP * 2));
    const float4* __restrict__ aw4  = (const float4*)(aw   + nqh * (LL * PP));
    float4 r[8], a[4];
#pragma unroll
    for (int i = 0; i < 8; ++i) r[i] = loc4[i];
#pragma unroll
    for (int i = 0; i < 4; ++i) a[i] = aw4[i];

    float4 acc = make_float4(0.f, 0.f, 0.f, 0.f);

#pragma unroll
    for (int l = 0; l < LL; ++l) {
        const int H = Hs[l];
        const int W = Ws[l];
        const float fW = (float)W, fH = (float)H;
        const float* __restrict__ vb =
            value + (((size_t)n * Lin + Ss[l]) * NH + h) * DD + c * 4;

        // level l uses loc floats [8l, 8l+8) = r[2l], r[2l+1]; aw floats a[l]
        const float4 rA = r[2 * l], rB = r[2 * l + 1];
        const float4 al = a[l];
        const float xs[PP] = { rA.x, rA.z, rB.x, rB.z };
        const float ys[PP] = { rA.y, rA.w, rB.y, rB.w };
        const float ws[PP] = { al.x, al.y, al.z, al.w };

        int   off[PP * 4];
        float wt [PP * 4];
#pragma unroll
        for (int p = 0; p < PP; ++p) {
            const float x = xs[p] * fW - 0.5f;
            const float y = ys[p] * fH - 0.5f;
            const float w = ws[p];

            const float x0f = floorf(x);
            const float y0f = floorf(y);
            const int x0 = (int)x0f;
            const int y0 = (int)y0f;
            const int x1 = x0 + 1;
            const int y1 = y0 + 1;
            const float dx = x - x0f;
            const float dy = y - y0f;

            const bool vx0 = (x0 >= 0) && (x0 < W);
            const bool vx1 = (x1 >= 0) && (x1 < W);
            const bool vy0 = (y0 >= 0) && (y0 < H);
            const bool vy1 = (y1 >= 0) && (y1 < H);

            const int cx0 = min(max(x0, 0), W - 1);
            const int cx1 = min(max(x1, 0), W - 1);
            const int cy0 = min(max(y0, 0), H - 1);
            const int cy1 = min(max(y1, 0), H - 1);

            off[4 * p + 0] = (cy0 * W + cx0) * PSTRIDE;
            off[4 * p + 1] = (cy0 * W + cx1) * PSTRIDE;
            off[4 * p + 2] = (cy1 * W + cx0) * PSTRIDE;
            off[4 * p + 3] = (cy1 * W + cx1) * PSTRIDE;

            wt[4 * p + 0] = (1.f - dx) * (1.f - dy) * w * ((vx0 && vy0) ? 1.f : 0.f);
            wt[4 * p + 1] = dx         * (1.f - dy) * w * ((vx1 && vy0) ? 1.f : 0.f);
            wt[4 * p + 2] = (1.f - dx) * dy         * w * ((vx0 && vy1) ? 1.f : 0.f);
            wt[4 * p + 3] = dx         * dy         * w * ((vx1 && vy1) ? 1.f : 0.f);
        }

        // issue all 16 gathers back-to-back, then accumulate
        float4 v[PP * 4];
#pragma unroll
        for (int k = 0; k < PP * 4; ++k)
            v[k] = *(const float4*)(vb + off[k]);
#pragma unroll
        for (int k = 0; k < PP * 4; ++k) {
            acc.x += wt[k] * v[k].x;
            acc.y += wt[k] * v[k].y;
            acc.z += wt[k] * v[k].z;
            acc.w += wt[k] * v[k].w;
        }
    }

    *(float4*)(out + nqh * DD + c * 4) = acc;
}

extern "C" void kernel_launch(void* const* d_in, const int* in_sizes, int n_in,
                              void* d_out, int out_size, void* d_ws, size_t ws_size,
                              hipStream_t stream)
{
    const float* value = (const float*)d_in[0];
    const int*   ss    = (const int*)  d_in[1];
    const int*   lsi   = (const int*)  d_in[2];
    const float* sloc  = (const float*)d_in[3];
    const float* aw    = (const float*)d_in[4];
    float* out = (float*)d_out;

    const int N = 2;
    const int Lq  = in_sizes[4] / (N * NH * LL * PP);
    const int Lin = in_sizes[0] / (N * NH * DD);

    const int total  = N * Lq * NH * 8;   // 8 float4 groups per (n,q,h)
    const int block  = 256;
    const int grid   = (total + block - 1) / block;

    msda_fwd<<<grid, block, 0, stream>>>(value, ss, lsi, sloc, aw, out,
                                         N, Lq, Lin, total);
}

// Round 3
// 174.185 us; speedup vs baseline: 1.0079x; 1.0079x over previous
//
#include <hip/hip_runtime.h>

// Multi-scale deformable attention forward.
// value:              (N, Lin, nH, D)        float32
// spatial_shapes:     (L, 2)                 int32/int64 (runtime-detected)
// level_start_index:  (L,)                   int32/int64 (runtime-detected)
// sampling_locations: (N, Lq, nH, L, P, 2)   float32
// attention_weights:  (N, Lq, nH, L, P)      float32
// out:                (N, Lq, nH*D)          float32
#define NH 8
#define DD 32
#define LL 4
#define PP 4

typedef float  f32x4  __attribute__((ext_vector_type(4)));
typedef _Float16 half8 __attribute__((ext_vector_type(8)));
typedef _Float16 half4v __attribute__((ext_vector_type(4)));

// ---------------- prepass: value (n,pos,h,d) fp32 -> (n,h,pos,d) fp16 ----------------
__global__ __launch_bounds__(256) void conv_kernel(
    const float* __restrict__ value, _Float16* __restrict__ vh,
    int Lin, int total)
{
    int tid = blockIdx.x * blockDim.x + threadIdx.x;
    if (tid >= total) return;
    const int d4  = tid & 7;               // 4-float group
    const int pos = (tid >> 3) % Lin;
    const int nh  = tid / (8 * Lin);       // n*NH + h
    const int n   = nh >> 3;
    const int h   = nh & 7;

    const f32x4 v = *(const f32x4*)(value + (((size_t)n * Lin + pos) * NH + h) * DD + d4 * 4);
    half4v o;
    o.x = (_Float16)v.x; o.y = (_Float16)v.y; o.z = (_Float16)v.z; o.w = (_Float16)v.w;
    *(half4v*)(vh + ((size_t)nh * Lin + pos) * DD + d4 * 4) = o;
}

// ---------------- main kernel (fp16 value, x-pair lanes) ----------------
// Unit = 8 lanes per (n,q,h): lane j -> side = j>>2 (x0 / x1 column),
// cg = j&3 -> channels [8*cg, 8*cg+8). Per point: 2 half8 loads (top/bot row).
// Rows are contiguous across the 8 lanes (x0 block | x1 block = 128 B).
__global__ __launch_bounds__(256) void msda_fwd_h(
    const _Float16* __restrict__ vh,
    const int*   __restrict__ spatial_shapes,
    const int*   __restrict__ level_start,
    const float* __restrict__ sloc,
    const float* __restrict__ aw,
    float*       __restrict__ out,
    int N, int Lq, int Lin, int total)
{
    int tid = blockIdx.x * blockDim.x + threadIdx.x;
    if (tid >= total) return;

    const int j    = tid & 7;
    const int side = j >> 2;
    const int cg   = j & 3;
    const int nqh  = tid >> 3;           // n*Lq*NH + q*NH + h
    const int h    = nqh & 7;
    const int n    = nqh / (Lq * NH);

    const bool is64 = (spatial_shapes[1] == 0);
    int Hs[LL], Ws[LL], Ss[LL];
#pragma unroll
    for (int l = 0; l < LL; ++l) {
        if (is64) {
            Hs[l] = spatial_shapes[4 * l];
            Ws[l] = spatial_shapes[4 * l + 2];
            Ss[l] = level_start[2 * l];
        } else {
            Hs[l] = spatial_shapes[2 * l];
            Ws[l] = spatial_shapes[2 * l + 1];
            Ss[l] = level_start[l];
        }
    }

    // loc/aw: streaming, nontemporal to avoid polluting L2
    const f32x4* __restrict__ loc4 = (const f32x4*)(sloc + (size_t)nqh * (LL * PP * 2));
    const f32x4* __restrict__ aw4  = (const f32x4*)(aw   + (size_t)nqh * (LL * PP));
    f32x4 r[8], a[4];
#pragma unroll
    for (int i = 0; i < 8; ++i) r[i] = __builtin_nontemporal_load(loc4 + i);
#pragma unroll
    for (int i = 0; i < 4; ++i) a[i] = __builtin_nontemporal_load(aw4 + i);

    const _Float16* __restrict__ vbase =
        vh + ((size_t)(n * NH + h) * Lin) * DD + cg * 8;

    float acc[8];
#pragma unroll
    for (int k = 0; k < 8; ++k) acc[k] = 0.f;

#pragma unroll
    for (int l = 0; l < LL; ++l) {
        const int H = Hs[l];
        const int W = Ws[l];
        const float fW = (float)W, fH = (float)H;
        const _Float16* __restrict__ vl = vbase + (size_t)Ss[l] * DD;

        const f32x4 rA = r[2 * l], rB = r[2 * l + 1];
        const f32x4 al = a[l];
        const float xs[PP] = { rA.x, rA.z, rB.x, rB.z };
        const float ys[PP] = { rA.y, rA.w, rB.y, rB.w };
        const float ws[PP] = { al.x, al.y, al.z, al.w };

#pragma unroll
        for (int p = 0; p < PP; ++p) {
            const float x = xs[p] * fW - 0.5f;
            const float y = ys[p] * fH - 0.5f;
            const float w = ws[p];

            const float x0f = floorf(x);
            const float y0f = floorf(y);
            const int x0 = (int)x0f;
            const int y0 = (int)y0f;
            const float dx = x - x0f;
            const float dy = y - y0f;

            const int   xc = x0 + side;              // this lane's column
            const bool  vx = (xc >= 0) && (xc < W);
            const int   cx = min(max(xc, 0), W - 1);
            const float wx = (side ? dx : (1.f - dx)) * (vx ? 1.f : 0.f) * w;

            const int y1 = y0 + 1;
            const bool vy0 = (y0 >= 0) && (y0 < H);
            const bool vy1 = (y1 >= 0) && (y1 < H);
            const int cy0 = min(max(y0, 0), H - 1);
            const int cy1 = min(max(y1, 0), H - 1);

            const float wtop = wx * (1.f - dy) * (vy0 ? 1.f : 0.f);
            const float wbot = wx * dy         * (vy1 ? 1.f : 0.f);

            const half8 top = *(const half8*)(vl + (size_t)(cy0 * W + cx) * DD);
            const half8 bot = *(const half8*)(vl + (size_t)(cy1 * W + cx) * DD);

#pragma unroll
            for (int k = 0; k < 8; ++k)
                acc[k] = fmaf((float)top[k], wtop, fmaf((float)bot[k], wbot, acc[k]));
        }
    }

    // merge x0/x1 partials: partner lane is j ^ 4
#pragma unroll
    for (int k = 0; k < 8; ++k)
        acc[k] += __shfl_xor(acc[k], 4);

    // store: lane j writes float4 at channel cg*8 + side*4  (8 lanes -> 128 B contiguous)
    f32x4 st;
    st.x = acc[side * 4 + 0];
    st.y = acc[side * 4 + 1];
    st.z = acc[side * 4 + 2];
    st.w = acc[side * 4 + 3];
    __builtin_nontemporal_store(st, (f32x4*)(out + (size_t)nqh * DD + cg * 8 + side * 4));
}

// ---------------- fp32 fallback (R2 kernel) if ws too small ----------------
__global__ __launch_bounds__(256) void msda_fwd_f32(
    const float* __restrict__ value,
    const int*   __restrict__ spatial_shapes,
    const int*   __restrict__ level_start,
    const float* __restrict__ sloc,
    const float* __restrict__ aw,
    float*       __restrict__ out,
    int N, int Lq, int Lin, int total)
{
    int tid = blockIdx.x * blockDim.x + threadIdx.x;
    if (tid >= total) return;
    const int c  = tid & 7;
    const int h  = (tid >> 3) & 7;
    const int nq = tid >> 6;
    const int n  = nq / Lq;
    const bool is64 = (spatial_shapes[1] == 0);
    int Hs[LL], Ws[LL], Ss[LL];
#pragma unroll
    for (int l = 0; l < LL; ++l) {
        if (is64) { Hs[l] = spatial_shapes[4*l]; Ws[l] = spatial_shapes[4*l+2]; Ss[l] = level_start[2*l]; }
        else      { Hs[l] = spatial_shapes[2*l]; Ws[l] = spatial_shapes[2*l+1]; Ss[l] = level_start[l]; }
    }
    const size_t nqh = (size_t)nq * NH + h;
    const float* loc_p = sloc + nqh * (LL * PP * 2);
    const float* aw_p  = aw   + nqh * (LL * PP);
    float4 acc = make_float4(0.f, 0.f, 0.f, 0.f);
#pragma unroll
    for (int l = 0; l < LL; ++l) {
        const int H = Hs[l], W = Ws[l];
        const float* vb = value + (((size_t)n * Lin + Ss[l]) * NH + h) * DD + c * 4;
#pragma unroll
        for (int p = 0; p < PP; ++p) {
            const int jj = l * PP + p;
            const float x = loc_p[2*jj] * (float)W - 0.5f;
            const float y = loc_p[2*jj+1] * (float)H - 0.5f;
            const float w = aw_p[jj];
            const float x0f = floorf(x), y0f = floorf(y);
            const int x0 = (int)x0f, y0 = (int)y0f, x1 = x0+1, y1 = y0+1;
            const float dx = x - x0f, dy = y - y0f;
            const bool vx0 = x0>=0 && x0<W, vx1 = x1>=0 && x1<W;
            const bool vy0 = y0>=0 && y0<H, vy1 = y1>=0 && y1<H;
            const int cx0 = min(max(x0,0),W-1), cx1 = min(max(x1,0),W-1);
            const int cy0 = min(max(y0,0),H-1), cy1 = min(max(y1,0),H-1);
            const float w00 = (1.f-dx)*(1.f-dy)*w*((vx0&&vy0)?1.f:0.f);
            const float w01 = dx*(1.f-dy)*w*((vx1&&vy0)?1.f:0.f);
            const float w10 = (1.f-dx)*dy*w*((vx0&&vy1)?1.f:0.f);
            const float w11 = dx*dy*w*((vx1&&vy1)?1.f:0.f);
            const float4 v00 = *(const float4*)(vb + (size_t)(cy0*W+cx0)*(NH*DD));
            const float4 v01 = *(const float4*)(vb + (size_t)(cy0*W+cx1)*(NH*DD));
            const float4 v10 = *(const float4*)(vb + (size_t)(cy1*W+cx0)*(NH*DD));
            const float4 v11 = *(const float4*)(vb + (size_t)(cy1*W+cx1)*(NH*DD));
            acc.x += w00*v00.x + w01*v01.x + w10*v10.x + w11*v11.x;
            acc.y += w00*v00.y + w01*v01.y + w10*v10.y + w11*v11.y;
            acc.z += w00*v00.z + w01*v01.z + w10*v10.z + w11*v11.z;
            acc.w += w00*v00.w + w01*v01.w + w10*v10.w + w11*v11.w;
        }
    }
    *(float4*)(out + nqh * DD + c * 4) = acc;
}

extern "C" void kernel_launch(void* const* d_in, const int* in_sizes, int n_in,
                              void* d_out, int out_size, void* d_ws, size_t ws_size,
                              hipStream_t stream)
{
    const float* value = (const float*)d_in[0];
    const int*   ss    = (const int*)  d_in[1];
    const int*   lsi   = (const int*)  d_in[2];
    const float* sloc  = (const float*)d_in[3];
    const float* aw    = (const float*)d_in[4];
    float* out = (float*)d_out;

    const int N = 2;
    const int Lq  = in_sizes[4] / (N * NH * LL * PP);
    const int Lin = in_sizes[0] / (N * NH * DD);

    const size_t need = (size_t)N * NH * Lin * DD * sizeof(_Float16);
    if (ws_size >= need) {
        _Float16* vh = (_Float16*)d_ws;
        const int ctotal = N * NH * Lin * 8;
        conv_kernel<<<(ctotal + 255) / 256, 256, 0, stream>>>(value, vh, Lin, ctotal);
        const int total = N * Lq * NH * 8;
        msda_fwd_h<<<(total + 255) / 256, 256, 0, stream>>>(vh, ss, lsi, sloc, aw, out,
                                                            N, Lq, Lin, total);
    } else {
        const int total = N * Lq * NH * 8;
        msda_fwd_f32<<<(total + 255) / 256, 256, 0, stream>>>(value, ss, lsi, sloc, aw, out,
                                                              N, Lq, Lin, total);
    }
}

// Round 4
// 165.280 us; speedup vs baseline: 1.0622x; 1.0539x over previous
//
#include <hip/hip_runtime.h>

// Multi-scale deformable attention forward.
// value:              (N, Lin, nH, D)        float32
// spatial_shapes:     (L, 2)                 int32/int64 (runtime-detected)
// level_start_index:  (L,)                   int32/int64 (runtime-detected)
// sampling_locations: (N, Lq, nH, L, P, 2)   float32
// attention_weights:  (N, Lq, nH, L, P)      float32
// out:                (N, Lq, nH*D)          float32
#define NH 8
#define DD 32
#define LL 4
#define PP 4

typedef float  f32x4  __attribute__((ext_vector_type(4)));
typedef _Float16 half8 __attribute__((ext_vector_type(8)));
typedef _Float16 half4v __attribute__((ext_vector_type(4)));

// ---------------- prepass: value (n,pos,h,d) fp32 -> (n,h,pos,d) fp16 ----------------
__global__ __launch_bounds__(256) void conv_kernel(
    const float* __restrict__ value, _Float16* __restrict__ vh,
    int Lin, int total)
{
    int tid = blockIdx.x * blockDim.x + threadIdx.x;
    if (tid >= total) return;
    const int d4  = tid & 7;
    const int pos = (tid >> 3) % Lin;
    const int nh  = tid / (8 * Lin);
    const int n   = nh >> 3;
    const int h   = nh & 7;

    const f32x4 v = *(const f32x4*)(value + (((size_t)n * Lin + pos) * NH + h) * DD + d4 * 4);
    half4v o;
    o.x = (_Float16)v.x; o.y = (_Float16)v.y; o.z = (_Float16)v.z; o.w = (_Float16)v.w;
    *(half4v*)(vh + ((size_t)nh * Lin + pos) * DD + d4 * 4) = o;
}

// ---------------- main kernel ----------------
// Block handles one (n,h) slab x 32 queries. blockIdx%8 picks the XCD
// (round-robin dispatch heuristic) so each XCD's L2 only ever sees
// slabsPerXcd slabs (2 x 720 KB = 1.44 MB << 4 MiB) -> gathers stay L2-hit.
// Unit = 8 lanes per query: lane j -> side=j>>2 (x0/x1 column), cg=j&3 ->
// channels [8cg,8cg+8). Per point: 2 half8 row loads (contiguous 128 B across
// the 8 lanes). 2-level software pipeline keeps ~16 gathers in flight.
__global__ __launch_bounds__(256) void msda_fwd_h(
    const _Float16* __restrict__ vh,
    const int*   __restrict__ spatial_shapes,
    const int*   __restrict__ level_start,
    const float* __restrict__ sloc,
    const float* __restrict__ aw,
    float*       __restrict__ out,
    int N, int Lq, int Lin, int spx, int nSlabs)
{
    const int xcd   = blockIdx.x & 7;
    const int blk   = blockIdx.x >> 3;
    const int sw    = blk % spx;
    const int chunk = blk / spx;
    const int slab  = xcd * spx + sw;          // n*NH + h
    if (slab >= nSlabs) return;

    const int j    = threadIdx.x & 7;
    const int side = j >> 2;
    const int cg   = j & 3;
    const int u    = threadIdx.x >> 3;
    const int q    = chunk * 32 + u;
    if (q >= Lq) return;

    const int n = slab >> 3;
    const int h = slab & 7;
    const size_t nqh = ((size_t)n * Lq + q) * NH + h;

    const bool is64 = (spatial_shapes[1] == 0);
    int Hs[LL], Ws[LL], Ss[LL];
#pragma unroll
    for (int l = 0; l < LL; ++l) {
        if (is64) {
            Hs[l] = spatial_shapes[4 * l];
            Ws[l] = spatial_shapes[4 * l + 2];
            Ss[l] = level_start[2 * l];
        } else {
            Hs[l] = spatial_shapes[2 * l];
            Ws[l] = spatial_shapes[2 * l + 1];
            Ss[l] = level_start[l];
        }
    }

    // streaming inputs: nontemporal so they don't evict vh from L2
    const f32x4* __restrict__ loc4 = (const f32x4*)(sloc + nqh * (LL * PP * 2));
    const f32x4* __restrict__ aw4  = (const f32x4*)(aw   + nqh * (LL * PP));
    f32x4 r[8], a[4];
#pragma unroll
    for (int i = 0; i < 8; ++i) r[i] = __builtin_nontemporal_load(loc4 + i);
#pragma unroll
    for (int i = 0; i < 4; ++i) a[i] = __builtin_nontemporal_load(aw4 + i);

    const _Float16* __restrict__ vbase = vh + (size_t)slab * Lin * DD + cg * 8;

    float acc[8];
#pragma unroll
    for (int k = 0; k < 8; ++k) acc[k] = 0.f;

#define CALC_LEVEL(l, OFF, WT, VL)                                           \
  {                                                                          \
    const int H = Hs[l], W = Ws[l];                                          \
    const float fW = (float)W, fH = (float)H;                                \
    VL = vbase + (size_t)Ss[l] * DD;                                         \
    const f32x4 rA = r[2*(l)], rB = r[2*(l)+1];                              \
    const f32x4 al = a[l];                                                   \
    const float xs[4] = { rA.x, rA.z, rB.x, rB.z };                          \
    const float ys[4] = { rA.y, rA.w, rB.y, rB.w };                          \
    const float wsv[4] = { al.x, al.y, al.z, al.w };                         \
    _Pragma("unroll")                                                        \
    for (int p = 0; p < 4; ++p) {                                            \
      const float x = xs[p]*fW - 0.5f, y = ys[p]*fH - 0.5f;                  \
      const float x0f = floorf(x), y0f = floorf(y);                          \
      const int x0 = (int)x0f, y0 = (int)y0f;                                \
      const float dx = x - x0f, dy = y - y0f;                                \
      const int xc = x0 + side;                                              \
      const bool vx = (xc >= 0) && (xc < W);                                 \
      const int cx = min(max(xc, 0), W - 1);                                 \
      const float wx = (side ? dx : (1.f - dx)) * (vx ? 1.f : 0.f) * wsv[p]; \
      const int y1 = y0 + 1;                                                 \
      const bool vy0 = (y0 >= 0) && (y0 < H);                                \
      const bool vy1 = (y1 >= 0) && (y1 < H);                                \
      const int cy0 = min(max(y0, 0), H - 1);                                \
      const int cy1 = min(max(y1, 0), H - 1);                                \
      OFF[2*p]   = (cy0 * W + cx) * DD;                                      \
      OFF[2*p+1] = (cy1 * W + cx) * DD;                                      \
      WT[2*p]    = wx * (1.f - dy) * (vy0 ? 1.f : 0.f);                      \
      WT[2*p+1]  = wx * dy         * (vy1 ? 1.f : 0.f);                      \
    }                                                                        \
  }

#define LOAD_LEVEL(OFF, VL, V)                                               \
  _Pragma("unroll")                                                          \
  for (int k = 0; k < 8; ++k) V[k] = *(const half8*)((VL) + OFF[k]);

#define ACC_LEVEL(WT, V)                                                     \
  _Pragma("unroll")                                                          \
  for (int k = 0; k < 8; ++k) {                                              \
    _Pragma("unroll")                                                        \
    for (int ch = 0; ch < 8; ++ch)                                           \
      acc[ch] = fmaf((float)V[k][ch], WT[k], acc[ch]);                       \
  }

    half8 vA[8], vB[8];
    const _Float16 *vlA, *vlB;
    int offA[8], offB[8];
    float wtA[8], wtB[8];

    CALC_LEVEL(0, offA, wtA, vlA)
    LOAD_LEVEL(offA, vlA, vA)
    CALC_LEVEL(1, offB, wtB, vlB)
    LOAD_LEVEL(offB, vlB, vB)
    ACC_LEVEL(wtA, vA)
    CALC_LEVEL(2, offA, wtA, vlA)
    LOAD_LEVEL(offA, vlA, vA)
    ACC_LEVEL(wtB, vB)
    CALC_LEVEL(3, offB, wtB, vlB)
    LOAD_LEVEL(offB, vlB, vB)
    ACC_LEVEL(wtA, vA)
    ACC_LEVEL(wtB, vB)

    // merge x0/x1 partials: partner lane is j ^ 4
#pragma unroll
    for (int k = 0; k < 8; ++k)
        acc[k] += __shfl_xor(acc[k], 4);

    f32x4 st;
    st.x = acc[side * 4 + 0];
    st.y = acc[side * 4 + 1];
    st.z = acc[side * 4 + 2];
    st.w = acc[side * 4 + 3];
    __builtin_nontemporal_store(st, (f32x4*)(out + nqh * DD + cg * 8 + side * 4));
}

// ---------------- fp32 fallback if ws too small ----------------
__global__ __launch_bounds__(256) void msda_fwd_f32(
    const float* __restrict__ value,
    const int*   __restrict__ spatial_shapes,
    const int*   __restrict__ level_start,
    const float* __restrict__ sloc,
    const float* __restrict__ aw,
    float*       __restrict__ out,
    int N, int Lq, int Lin, int total)
{
    int tid = blockIdx.x * blockDim.x + threadIdx.x;
    if (tid >= total) return;
    const int c  = tid & 7;
    const int h  = (tid >> 3) & 7;
    const int nq = tid >> 6;
    const int n  = nq / Lq;
    const bool is64 = (spatial_shapes[1] == 0);
    int Hs[LL], Ws[LL], Ss[LL];
#pragma unroll
    for (int l = 0; l < LL; ++l) {
        if (is64) { Hs[l] = spatial_shapes[4*l]; Ws[l] = spatial_shapes[4*l+2]; Ss[l] = level_start[2*l]; }
        else      { Hs[l] = spatial_shapes[2*l]; Ws[l] = spatial_shapes[2*l+1]; Ss[l] = level_start[l]; }
    }
    const size_t nqh = (size_t)nq * NH + h;
    const float* loc_p = sloc + nqh * (LL * PP * 2);
    const float* aw_p  = aw   + nqh * (LL * PP);
    float4 acc = make_float4(0.f, 0.f, 0.f, 0.f);
#pragma unroll
    for (int l = 0; l < LL; ++l) {
        const int H = Hs[l], W = Ws[l];
        const float* vb = value + (((size_t)n * Lin + Ss[l]) * NH + h) * DD + c * 4;
#pragma unroll
        for (int p = 0; p < PP; ++p) {
            const int jj = l * PP + p;
            const float x = loc_p[2*jj] * (float)W - 0.5f;
            const float y = loc_p[2*jj+1] * (float)H - 0.5f;
            const float w = aw_p[jj];
            const float x0f = floorf(x), y0f = floorf(y);
            const int x0 = (int)x0f, y0 = (int)y0f, x1 = x0+1, y1 = y0+1;
            const float dx = x - x0f, dy = y - y0f;
            const bool vx0 = x0>=0 && x0<W, vx1 = x1>=0 && x1<W;
            const bool vy0 = y0>=0 && y0<H, vy1 = y1>=0 && y1<H;
            const int cx0 = min(max(x0,0),W-1), cx1 = min(max(x1,0),W-1);
            const int cy0 = min(max(y0,0),H-1), cy1 = min(max(y1,0),H-1);
            const float w00 = (1.f-dx)*(1.f-dy)*w*((vx0&&vy0)?1.f:0.f);
            const float w01 = dx*(1.f-dy)*w*((vx1&&vy0)?1.f:0.f);
            const float w10 = (1.f-dx)*dy*w*((vx0&&vy1)?1.f:0.f);
            const float w11 = dx*dy*w*((vx1&&vy1)?1.f:0.f);
            const float4 v00 = *(const float4*)(vb + (size_t)(cy0*W+cx0)*(NH*DD));
            const float4 v01 = *(const float4*)(vb + (size_t)(cy0*W+cx1)*(NH*DD));
            const float4 v10 = *(const float4*)(vb + (size_t)(cy1*W+cx0)*(NH*DD));
            const float4 v11 = *(const float4*)(vb + (size_t)(cy1*W+cx1)*(NH*DD));
            acc.x += w00*v00.x + w01*v01.x + w10*v10.x + w11*v11.x;
            acc.y += w00*v00.y + w01*v01.y + w10*v10.y + w11*v11.y;
            acc.z += w00*v00.z + w01*v01.z + w10*v10.z + w11*v11.z;
            acc.w += w00*v00.w + w01*v01.w + w10*v10.w + w11*v11.w;
        }
    }
    *(float4*)(out + nqh * DD + c * 4) = acc;
}

extern "C" void kernel_launch(void* const* d_in, const int* in_sizes, int n_in,
                              void* d_out, int out_size, void* d_ws, size_t ws_size,
                              hipStream_t stream)
{
    const float* value = (const float*)d_in[0];
    const int*   ss    = (const int*)  d_in[1];
    const int*   lsi   = (const int*)  d_in[2];
    const float* sloc  = (const float*)d_in[3];
    const float* aw    = (const float*)d_in[4];
    float* out = (float*)d_out;

    const int N = 2;
    const int Lq  = in_sizes[4] / (N * NH * LL * PP);
    const int Lin = in_sizes[0] / (N * NH * DD);

    const size_t need = (size_t)N * NH * Lin * DD * sizeof(_Float16);
    if (ws_size >= need) {
        _Float16* vh = (_Float16*)d_ws;
        const int ctotal = N * NH * Lin * 8;
        conv_kernel<<<(ctotal + 255) / 256, 256, 0, stream>>>(value, vh, Lin, ctotal);

        const int nSlabs = N * NH;              // 16
        const int spx    = (nSlabs + 7) / 8;    // slabs per XCD = 2
        const int chunks = (Lq + 31) / 32;
        const int grid   = 8 * spx * chunks;
        msda_fwd_h<<<grid, 256, 0, stream>>>(vh, ss, lsi, sloc, aw, out,
                                             N, Lq, Lin, spx, nSlabs);
    } else {
        const int total = N * Lq * NH * 8;
        msda_fwd_f32<<<(total + 255) / 256, 256, 0, stream>>>(value, ss, lsi, sloc, aw, out,
                                                              N, Lq, Lin, total);
    }
}

// Round 5
// 135.317 us; speedup vs baseline: 1.2974x; 1.2214x over previous
//
#include <hip/hip_runtime.h>

// Multi-scale deformable attention forward.
// value:              (N, Lin, nH, D)        float32
// spatial_shapes:     (L, 2)                 int32/int64 (runtime-detected)
// level_start_index:  (L,)                   int32/int64 (runtime-detected)
// sampling_locations: (N, Lq, nH, L, P, 2)   float32
// attention_weights:  (N, Lq, nH, L, P)      float32
// out:                (N, Lq, nH*D)          float32
#define NH 8
#define DD 32
#define LL 4
#define PP 4

typedef float  f32x4  __attribute__((ext_vector_type(4)));
typedef float  f32x2  __attribute__((ext_vector_type(2)));
typedef int    i32x4  __attribute__((ext_vector_type(4)));
typedef _Float16 half8 __attribute__((ext_vector_type(8)));
typedef _Float16 half4v __attribute__((ext_vector_type(4)));

// ---------------- prepass: value (n,pos,h,d) fp32 -> (n,h,pos,d) fp16 ----------------
__global__ __launch_bounds__(256) void conv_kernel(
    const float* __restrict__ value, _Float16* __restrict__ vh,
    int Lin, int total)
{
    int tid = blockIdx.x * blockDim.x + threadIdx.x;
    if (tid >= total) return;
    const int d4  = tid & 7;
    const int pos = (tid >> 3) % Lin;
    const int nh  = tid / (8 * Lin);
    const int n   = nh >> 3;
    const int h   = nh & 7;

    const f32x4 v = *(const f32x4*)(value + (((size_t)n * Lin + pos) * NH + h) * DD + d4 * 4);
    half4v o;
    o.x = (_Float16)v.x; o.y = (_Float16)v.y; o.z = (_Float16)v.z; o.w = (_Float16)v.w;
    *(half4v*)(vh + ((size_t)nh * Lin + pos) * DD + d4 * 4) = o;
}

// ---------------- main kernel ----------------
// Block = one (n,h) slab x 32 queries; blockIdx%8 -> XCD so each XCD's L2
// holds only 2 slabs (1.44 MB) -> gathers stay L2-hit (verified R4:
// FETCH_SIZE dropped to the stream floor).
//
// Phase 1: 256 threads compute coordinate math ONCE per (unit, point)
// (2 points/thread), prebaking {off_top, off_bot, w_top, w_bot} per side
// into LDS (byte offsets, level start folded in -> phase 2 needs no shapes).
// Phase 2: lane j of unit u (side=j>>2, cg=j&3) does per point:
// 1 ds_read_b128 + 2 saddr global_load_dwordx4 + 16 fma_mix.
// amdgpu_waves_per_eu(3,4) caps occupancy so the scheduler keeps the
// double-buffered 4-point batches (8 loads) in flight instead of sinking them.
__global__ __attribute__((amdgpu_flat_work_group_size(256, 256)))
__attribute__((amdgpu_waves_per_eu(3, 4)))
void msda_fwd_h(
    const _Float16* __restrict__ vh,
    const int*   __restrict__ ssh,
    const int*   __restrict__ lsi,
    const float* __restrict__ sloc,
    const float* __restrict__ aw,
    float*       __restrict__ out,
    int N, int Lq, int Lin, int spx, int nSlabs)
{
    __shared__ i32x4 ent[32 * 33];   // [unit][point*2+side], +1 entry pad per unit

    const int xcd   = blockIdx.x & 7;
    const int blk   = blockIdx.x >> 3;
    const int sw    = blk % spx;
    const int chunk = blk / spx;
    const int slab  = xcd * spx + sw;          // n*NH + h  (block-uniform)
    if (slab >= nSlabs) return;                // uniform -> barrier-safe

    const int t  = threadIdx.x;
    const int u  = t >> 3;                     // unit (query) within block
    const int j  = t & 7;
    const int q  = chunk * 32 + u;
    const int qc = min(q, Lq - 1);
    const int n  = slab >> 3;
    const int h  = slab & 7;

    // ---- phase 1: compute points p = 2j, 2j+1 of unit u (both sides) ----
    {
        const size_t nqh = ((size_t)n * Lq + qc) * NH + h;
        const int l = j >> 1;                  // both points share a level
        const bool is64 = (ssh[1] == 0);
        const int W = is64 ? ssh[4 * l + 2] : ssh[2 * l + 1];
        const int H = is64 ? ssh[4 * l]     : ssh[2 * l];
        const int S = is64 ? lsi[2 * l]     : lsi[l];
        const f32x4 lc = __builtin_nontemporal_load((const f32x4*)sloc + nqh * 8 + j);
        const f32x2 av = __builtin_nontemporal_load((const f32x2*)aw + nqh * 8 + j);
        const float fW = (float)W, fH = (float)H;
        const int rowb  = W * (DD * 2);
        const int sbase = S * (DD * 2);
#pragma unroll
        for (int pt = 0; pt < 2; ++pt) {
            const float x  = lc[2 * pt]     * fW - 0.5f;
            const float y  = lc[2 * pt + 1] * fH - 0.5f;
            const float wq = av[pt];
            const float x0f = floorf(x), y0f = floorf(y);
            const int x0 = (int)x0f, y0 = (int)y0f;
            const float dx = x - x0f, dy = y - y0f;
            const int x1 = x0 + 1, y1 = y0 + 1;
            const bool vx0 = (x0 >= 0) & (x0 < W), vx1 = (x1 >= 0) & (x1 < W);
            const bool vy0 = (y0 >= 0) & (y0 < H), vy1 = (y1 >= 0) & (y1 < H);
            const int cx0 = min(max(x0, 0), W - 1), cx1 = min(max(x1, 0), W - 1);
            const int cy0 = min(max(y0, 0), H - 1), cy1 = min(max(y1, 0), H - 1);
            const float wx0 = (1.f - dx) * wq * (vx0 ? 1.f : 0.f);
            const float wx1 = dx         * wq * (vx1 ? 1.f : 0.f);
            const float ty  = (1.f - dy) * (vy0 ? 1.f : 0.f);
            const float by  = dy         * (vy1 ? 1.f : 0.f);
            const int rt = cy0 * rowb + sbase;
            const int rb = cy1 * rowb + sbase;
            const int p  = 2 * j + pt;
            i32x4 e0, e1;
            e0.x = rt + cx0 * (DD * 2);  e0.y = rb + cx0 * (DD * 2);
            e0.z = __float_as_int(wx0 * ty);  e0.w = __float_as_int(wx0 * by);
            e1.x = rt + cx1 * (DD * 2);  e1.y = rb + cx1 * (DD * 2);
            e1.z = __float_as_int(wx1 * ty);  e1.w = __float_as_int(wx1 * by);
            ent[u * 33 + 2 * p]     = e0;
            ent[u * 33 + 2 * p + 1] = e1;
        }
    }
    __syncthreads();
    if (q >= Lq) return;

    // ---- phase 2 ----
    const int side = j >> 2;
    const int cg   = j & 3;
    const int cg16 = cg * 16;                   // byte offset of channel group
    const char* __restrict__ sb =
        (const char*)vh + (size_t)slab * Lin * (DD * 2);   // scalar base -> saddr loads
    const int ub = u * 33 + side;

    float acc[8];
#pragma unroll
    for (int k = 0; k < 8; ++k) acc[k] = 0.f;

#define RD(b, E) _Pragma("unroll") \
    for (int i = 0; i < 4; ++i) E[i] = ent[ub + 2 * (4 * (b) + i)];
#define LD(E, V) _Pragma("unroll") \
    for (int i = 0; i < 4; ++i) { \
        V[2*i]   = *(const half8*)(sb + (unsigned)(E[i].x + cg16)); \
        V[2*i+1] = *(const half8*)(sb + (unsigned)(E[i].y + cg16)); }
#define AC(E, V) _Pragma("unroll") \
    for (int i = 0; i < 4; ++i) { \
        const float wt = __int_as_float(E[i].z); \
        const float wb = __int_as_float(E[i].w); \
        _Pragma("unroll") for (int ch = 0; ch < 8; ++ch) \
            acc[ch] = fmaf((float)V[2*i][ch], wt, fmaf((float)V[2*i+1][ch], wb, acc[ch])); }

    i32x4 E0[4], E1[4], E2[4], E3[4];
    half8 V0[8], V1[8], V2[8], V3[8];
    RD(0, E0) LD(E0, V0)
    RD(1, E1) LD(E1, V1)
    AC(E0, V0)
    RD(2, E2) LD(E2, V2)
    AC(E1, V1)
    RD(3, E3) LD(E3, V3)
    AC(E2, V2)
    AC(E3, V3)

    // merge x0/x1 partials: partner lane is j ^ 4
#pragma unroll
    for (int k = 0; k < 8; ++k)
        acc[k] += __shfl_xor(acc[k], 4);

    f32x4 st;
    st.x = acc[side * 4 + 0];
    st.y = acc[side * 4 + 1];
    st.z = acc[side * 4 + 2];
    st.w = acc[side * 4 + 3];
    const size_t onqh = ((size_t)n * Lq + q) * NH + h;
    __builtin_nontemporal_store(st, (f32x4*)(out + onqh * DD + cg * 8 + side * 4));
}

// ---------------- fp32 fallback if ws too small ----------------
__global__ __launch_bounds__(256) void msda_fwd_f32(
    const float* __restrict__ value,
    const int*   __restrict__ spatial_shapes,
    const int*   __restrict__ level_start,
    const float* __restrict__ sloc,
    const float* __restrict__ aw,
    float*       __restrict__ out,
    int N, int Lq, int Lin, int total)
{
    int tid = blockIdx.x * blockDim.x + threadIdx.x;
    if (tid >= total) return;
    const int c  = tid & 7;
    const int h  = (tid >> 3) & 7;
    const int nq = tid >> 6;
    const int n  = nq / Lq;
    const bool is64 = (spatial_shapes[1] == 0);
    int Hs[LL], Ws[LL], Ss[LL];
#pragma unroll
    for (int l = 0; l < LL; ++l) {
        if (is64) { Hs[l] = spatial_shapes[4*l]; Ws[l] = spatial_shapes[4*l+2]; Ss[l] = level_start[2*l]; }
        else      { Hs[l] = spatial_shapes[2*l]; Ws[l] = spatial_shapes[2*l+1]; Ss[l] = level_start[l]; }
    }
    const size_t nqh = (size_t)nq * NH + h;
    const float* loc_p = sloc + nqh * (LL * PP * 2);
    const float* aw_p  = aw   + nqh * (LL * PP);
    float4 acc = make_float4(0.f, 0.f, 0.f, 0.f);
#pragma unroll
    for (int l = 0; l < LL; ++l) {
        const int H = Hs[l], W = Ws[l];
        const float* vb = value + (((size_t)n * Lin + Ss[l]) * NH + h) * DD + c * 4;
#pragma unroll
        for (int p = 0; p < PP; ++p) {
            const int jj = l * PP + p;
            const float x = loc_p[2*jj] * (float)W - 0.5f;
            const float y = loc_p[2*jj+1] * (float)H - 0.5f;
            const float w = aw_p[jj];
            const float x0f = floorf(x), y0f = floorf(y);
            const int x0 = (int)x0f, y0 = (int)y0f, x1 = x0+1, y1 = y0+1;
            const float dx = x - x0f, dy = y - y0f;
            const bool vx0 = x0>=0 && x0<W, vx1 = x1>=0 && x1<W;
            const bool vy0 = y0>=0 && y0<H, vy1 = y1>=0 && y1<H;
            const int cx0 = min(max(x0,0),W-1), cx1 = min(max(x1,0),W-1);
            const int cy0 = min(max(y0,0),H-1), cy1 = min(max(y1,0),H-1);
            const float w00 = (1.f-dx)*(1.f-dy)*w*((vx0&&vy0)?1.f:0.f);
            const float w01 = dx*(1.f-dy)*w*((vx1&&vy0)?1.f:0.f);
            const float w10 = (1.f-dx)*dy*w*((vx0&&vy1)?1.f:0.f);
            const float w11 = dx*dy*w*((vx1&&vy1)?1.f:0.f);
            const float4 v00 = *(const float4*)(vb + (size_t)(cy0*W+cx0)*(NH*DD));
            const float4 v01 = *(const float4*)(vb + (size_t)(cy0*W+cx1)*(NH*DD));
            const float4 v10 = *(const float4*)(vb + (size_t)(cy1*W+cx0)*(NH*DD));
            const float4 v11 = *(const float4*)(vb + (size_t)(cy1*W+cx1)*(NH*DD));
            acc.x += w00*v00.x + w01*v01.x + w10*v10.x + w11*v11.x;
            acc.y += w00*v00.y + w01*v01.y + w10*v10.y + w11*v11.y;
            acc.z += w00*v00.z + w01*v01.z + w10*v10.z + w11*v11.z;
            acc.w += w00*v00.w + w01*v01.w + w10*v10.w + w11*v11.w;
        }
    }
    *(float4*)(out + nqh * DD + c * 4) = acc;
}

extern "C" void kernel_launch(void* const* d_in, const int* in_sizes, int n_in,
                              void* d_out, int out_size, void* d_ws, size_t ws_size,
                              hipStream_t stream)
{
    const float* value = (const float*)d_in[0];
    const int*   ss    = (const int*)  d_in[1];
    const int*   lsi   = (const int*)  d_in[2];
    const float* sloc  = (const float*)d_in[3];
    const float* aw    = (const float*)d_in[4];
    float* out = (float*)d_out;

    const int N = 2;
    const int Lq  = in_sizes[4] / (N * NH * LL * PP);
    const int Lin = in_sizes[0] / (N * NH * DD);

    const size_t need = (size_t)N * NH * Lin * DD * sizeof(_Float16);
    if (ws_size >= need) {
        _Float16* vh = (_Float16*)d_ws;
        const int ctotal = N * NH * Lin * 8;
        conv_kernel<<<(ctotal + 255) / 256, 256, 0, stream>>>(value, vh, Lin, ctotal);

        const int nSlabs = N * NH;              // 16
        const int spx    = (nSlabs + 7) / 8;    // slabs per XCD = 2
        const int chunks = (Lq + 31) / 32;
        const int grid   = 8 * spx * chunks;
        msda_fwd_h<<<grid, 256, 0, stream>>>(vh, ss, lsi, sloc, aw, out,
                                             N, Lq, Lin, spx, nSlabs);
    } else {
        const int total = N * Lq * NH * 8;
        msda_fwd_f32<<<(total + 255) / 256, 256, 0, stream>>>(value, ss, lsi, sloc, aw, out,
                                                              N, Lq, Lin, total);
    }
}